// Round 13
// baseline (11241.454 us; speedup 1.0000x reference)
//
#include <hip/hip_runtime.h>
#include <math.h>
#include <stdint.h>

namespace {

typedef __attribute__((ext_vector_type(8))) short short8v;   // 8 bf16 = 4 VGPR
typedef __attribute__((ext_vector_type(4))) float f32x4;

constexpr int TT = 256;

// ---- BIG path float offsets (pre-split weights), total 14,532,608 fl = 58.1 MB ----
constexpr size_t B_ST   = 0;          // c0T,h1T,c1T [3][64][512]
constexpr size_t B_P0   = 98304;      // [4][64][6144]
constexpr size_t B_P1   = 1671168;    // [4][64][6144]
constexpr size_t B_FEAT = 3244032;    // 2,129,920 ushorts
constexpr size_t B_WSP  = 4308992;    // 20,447,232 ushorts (split weights)
constexpr size_t WS_BIG = (B_WSP + 10223616) * 4;

// ushort offsets inside wsplit
constexpr size_t WIH0H = 0,        WIH0L = 196608;
constexpr size_t WHH0H = 393216,   WHH0L = 1179648;
constexpr size_t KB0H  = 1966080,  KB0L  = 2293760;
constexpr size_t SWT0H = 2621440,  SWT0L = 5242880;     // [8][512][640]
constexpr size_t WIH1H = 7864320,  WIH1L = 8650752;
constexpr size_t WHH1H = 9437184,  WHH1L = 10223616;
constexpr size_t KB1H  = 11010048, KB1L  = 11534336;
constexpr size_t SWT1H = 12058624, SWT1L = 16252928;    // [8][512][1024]

// ---- SMALL path float offsets (round-12 proven, 38.2 MB) ----
constexpr size_t S_ST   = 0;
constexpr size_t S_P0   = 98304;      // [2][64][6144]
constexpr size_t S_P1   = 884736;
constexpr size_t S_SWT0 = 1671168;    // [8][512][640] fp32
constexpr size_t S_SWT1 = 4292608;    // [8][512][1024] fp32
constexpr size_t S_FEAT = 8486912;
constexpr size_t WS_SMALL = 9551872ull * 4;

// ---- ushort offsets within FEAT (both paths) ----
constexpr size_t FZ0H = 0,       FZ0L = 40960,  FS0H = 81920,  FS0L = 122880;
constexpr size_t FB0H = 163840,  FB0L = 491520;                 // planes 64*640
constexpr size_t L1F  = 819200;
constexpr size_t FZ1H = L1F,          FZ1L = L1F + 65536;
constexpr size_t FS1H = L1F + 131072, FS1L = L1F + 196608;
constexpr size_t FB1H = L1F + 262144, FB1L = L1F + 786432;      // planes 64*1024

__device__ __forceinline__ float sigmoidf_(float v) { return 1.0f / (1.0f + expf(-v)); }

__device__ __forceinline__ ushort bf16h(float v) {          // RNE f32 -> bf16 bits
    uint32_t u = __float_as_uint(v);
    return (ushort)((u + 0x7fffu + ((u >> 16) & 1u)) >> 16);
}
__device__ __forceinline__ float bf16f(ushort h) { return __uint_as_float(((uint32_t)h) << 16); }
__device__ __forceinline__ void put2(ushort* hi, ushort* lo, size_t idx, float v) {
    ushort h = bf16h(v); hi[idx] = h; lo[idx] = bf16h(v - bf16f(h));
}

// Cox-de Boor, GRID_SIZE=5, ORDER=3 (verified rounds 7-12)
__device__ __forceinline__ void bspline8(float x, float* out) {
    const float KG[12] = {-2.2f,-1.8f,-1.4f,-1.0f,-0.6f,-0.2f,
                           0.2f, 0.6f, 1.0f, 1.4f, 1.8f, 2.2f};
    float b[11];
#pragma unroll
    for (int i = 0; i < 11; ++i)
        b[i] = (x >= KG[i] && x < KG[i + 1]) ? 1.0f : 0.0f;
#pragma unroll
    for (int p = 1; p <= 3; ++p) {
#pragma unroll
        for (int i = 0; i + p < 11; ++i) {
            float l = (x - KG[i])         * (1.0f / (KG[i + p] - KG[i]));
            float r = (KG[i + p + 1] - x) * (1.0f / (KG[i + p + 1] - KG[i + 1]));
            b[i] = l * b[i] + r * b[i + 1];
        }
    }
#pragma unroll
    for (int i = 0; i < 8; ++i) out[i] = b[i];
}

__device__ __forceinline__ void write_featsT(float z, ushort* fe,
        size_t zh, size_t zl, size_t sh, size_t sl, size_t bh, size_t bl,
        size_t pstride, size_t idx)
{
    put2(fe + zh, fe + zl, idx, z);
    put2(fe + sh, fe + sl, idx, z / (1.0f + expf(-z)));
    float bs[8];
    bspline8(z, bs);
#pragma unroll
    for (int r = 0; r < 8; ++r)
        put2(fe + bh + (size_t)r * pstride, fe + bl + (size_t)r * pstride, idx, bs[r]);
}

__global__ __launch_bounds__(256) void sentinel_kernel(float* out, float v) {
    int i = blockIdx.x * 256 + threadIdx.x;
    if (i < 8192) out[i] = v;
}

// states zero + t=0 x-features + zero-state hidden features for both layers
__global__ __launch_bounds__(256) void prologue_kernel(
    const float* __restrict__ x, float* __restrict__ st, ushort* __restrict__ fe)
{
    const int g = blockIdx.x * 256 + threadIdx.x;    // 672*256 = 172032
    if (g < 98304) {
        st[g] = 0.0f;                                // c0T,h1T,c1T
    } else if (g < 106496) {                         // t=0 x feats (k<128)
        const int i = g - 98304, k = i & 127, b = i >> 7;
        write_featsT(x[((size_t)b * TT) * 128 + k], fe,
                     FZ0H, FZ0L, FS0H, FS0L, FB0H, FB0L, 40960, (size_t)b * 640 + k);
    } else if (g < 139264) {                         // L0 hidden feats h0(-1)=0
        const int i = g - 106496, o = i & 511, b = i >> 9;
        write_featsT(0.0f, fe, FZ0H, FZ0L, FS0H, FS0L, FB0H, FB0L,
                     40960, (size_t)b * 640 + 128 + o);
    } else {                                         // L1 hidden feats h1(-1)=0
        const int i = g - 139264, o = i & 511, b = i >> 9;
        write_featsT(0.0f, fe, FZ1H, FZ1L, FS1H, FS1L, FB1H, FB1L,
                     65536, (size_t)b * 1024 + 512 + o);
    }
}

// ---- setup: weight split kernels (big path) ----
__global__ __launch_bounds__(256) void split_plain(
    const float* __restrict__ src, ushort* __restrict__ hi, ushort* __restrict__ lo, int n)
{
    const int i = blockIdx.x * 256 + threadIdx.x;
    if (i < n) {
        float v = src[i];
        ushort h = bf16h(v);
        hi[i] = h; lo[i] = bf16h(v - bf16f(h));
    }
}

// ksp [512][W][8] -> hi/lo [8][512][W]
template <int W>
__global__ __launch_bounds__(256) void split_swT(
    const float* __restrict__ sw, ushort* __restrict__ hi, ushort* __restrict__ lo)
{
    const int i = blockIdx.x * 256 + threadIdx.x;   // over 512*W
    float v[8];
#pragma unroll
    for (int r = 0; r < 8; ++r) v[r] = sw[(size_t)i * 8 + r];
#pragma unroll
    for (int r = 0; r < 8; ++r) {
        ushort h = bf16h(v[r]);
        hi[(size_t)r * 512 * W + i] = h;
        lo[(size_t)r * 512 * W + i] = bf16h(v[r] - bf16f(h));
    }
}

// sw [512][W][8] -> swT [8][512][W] fp32 (small path)
template <int W>
__global__ __launch_bounds__(256) void transpose_sw(const float* __restrict__ sw,
                                                    float* __restrict__ swT) {
    const int i = blockIdx.x * 256 + threadIdx.x;
    float v[8];
#pragma unroll
    for (int r = 0; r < 8; ++r) v[r] = sw[(size_t)i * 8 + r];
#pragma unroll
    for (int r = 0; r < 8; ++r) swT[(size_t)r * 512 * W + i] = v[r];
}

// ==== BIG path phase A: pre-split weights, K-quarters, 768 blocks x 256 thr ====
// 3072 wave-tasks = 2 layers x 384 row-tiles x 4 kq. Pure loads + MFMA.
__global__ __launch_bounds__(256) void phaseA_ps(
    const ushort* __restrict__ fe, const ushort* __restrict__ wsp,
    float* __restrict__ p0, float* __restrict__ p1, int s)
{
    const int lane = threadIdx.x & 63;
    const int wv   = __builtin_amdgcn_readfirstlane((int)(threadIdx.x >> 6));
    const int wid  = blockIdx.x * 4 + wv;            // 0..3071
    const bool isL1 = wid >= 1536;
    if (isL1 ? (s < 1) : (s >= TT)) return;
    const int r    = isL1 ? wid - 1536 : wid;
    const int tile = r >> 2, kq = r & 3;
    const int IN = isL1 ? 512 : 128, W = IN + 512, KC = W >> 2, NSL = KC >> 5;

    float* p = (isL1 ? p1 : p0) + (size_t)kq * 393216;
    const int m = lane & 15, kg = lane >> 4;
    const int o0 = tile * 16;

    const ushort *wa_h, *wa_l, *wb_h = nullptr, *wb_l = nullptr, *fhi, *flo;
    if (tile < 96) {                                  // gate rows
        const size_t ra = (size_t)(o0 + m) * IN, rb = (size_t)(o0 + m) * 512;
        wa_h = wsp + (isL1 ? WIH1H : WIH0H) + ra;  wa_l = wsp + (isL1 ? WIH1L : WIH0L) + ra;
        wb_h = wsp + (isL1 ? WHH1H : WHH0H) + rb;  wb_l = wsp + (isL1 ? WHH1L : WHH0L) + rb;
        fhi = fe + (isL1 ? FZ1H : FZ0H);  flo = fe + (isL1 ? FZ1L : FZ0L);
    } else if (tile < 128) {                          // base rows
        const size_t ro = (size_t)((tile - 96) * 16 + m) * W;
        wa_h = wsp + (isL1 ? KB1H : KB0H) + ro;  wa_l = wsp + (isL1 ? KB1L : KB0L) + ro;
        fhi = fe + (isL1 ? FS1H : FS0H);  flo = fe + (isL1 ? FS1L : FS0L);
    } else {                                          // spline rows
        const int rr = (tile - 128) >> 5, op = ((tile - 128) & 31) * 16 + m;
        const size_t ro = ((size_t)rr * 512 + op) * W;
        wa_h = wsp + (isL1 ? SWT1H : SWT0H) + ro;  wa_l = wsp + (isL1 ? SWT1L : SWT0L) + ro;
        fhi = fe + (isL1 ? FB1H : FB0H) + (size_t)rr * 64 * W;
        flo = fe + (isL1 ? FB1L : FB0L) + (size_t)rr * 64 * W;
    }

    f32x4 acc[4] = {{0,0,0,0},{0,0,0,0},{0,0,0,0},{0,0,0,0}};
    const int kbase = kq * KC;

    for (int sl = 0; sl < NSL; ++sl) {
        const int k0 = kbase + sl * 32;
        const int kk = k0 + kg * 8;
        short8v whi, wlo;
        if (tile < 96 && k0 >= IN) {
            whi = *(const short8v*)(wb_h + (kk - IN));
            wlo = *(const short8v*)(wb_l + (kk - IN));
        } else {
            whi = *(const short8v*)(wa_h + kk);
            wlo = *(const short8v*)(wa_l + kk);
        }
#pragma unroll
        for (int bt = 0; bt < 4; ++bt) {
            const size_t fidx = (size_t)(bt * 16 + m) * W + kk;
            short8v bh = *(const short8v*)(fhi + fidx);
            short8v bl = *(const short8v*)(flo + fidx);
            acc[bt] = __builtin_amdgcn_mfma_f32_16x16x32_bf16(whi, bh, acc[bt], 0, 0, 0);
            acc[bt] = __builtin_amdgcn_mfma_f32_16x16x32_bf16(whi, bl, acc[bt], 0, 0, 0);
            acc[bt] = __builtin_amdgcn_mfma_f32_16x16x32_bf16(wlo, bh, acc[bt], 0, 0, 0);
        }
    }

#pragma unroll
    for (int bt = 0; bt < 4; ++bt) {
        float* dst = p + (size_t)(bt * 16 + m) * 6144 + o0 + kg * 4;
        *(float4*)dst = (float4){acc[bt][0], acc[bt][1], acc[bt][2], acc[bt][3]};
    }
}

// ==== SMALL path phase A: round-12 on-the-fly split, K-halves ====
__global__ __launch_bounds__(128) void phaseA_fb(
    const ushort* __restrict__ fe,
    const float* __restrict__ swt0, const float* __restrict__ swt1,
    float* __restrict__ p0, float* __restrict__ p1,
    const float* __restrict__ w_ih0, const float* __restrict__ w_hh0,
    const float* __restrict__ kb0,
    const float* __restrict__ w_ih1, const float* __restrict__ w_hh1,
    const float* __restrict__ kb1, int s)
{
    const int lane = threadIdx.x & 63;
    const int wv   = __builtin_amdgcn_readfirstlane((int)(threadIdx.x >> 6));
    const int wid  = blockIdx.x * 2 + wv;            // 0..1535
    const bool isL1 = wid >= 768;
    if (isL1 ? (s < 1) : (s >= TT)) return;
    const int r    = isL1 ? wid - 768 : wid;
    const int tile = r >> 1, khalf = r & 1;
    const int IN = isL1 ? 512 : 128, W = IN + 512, KC = W >> 1, NSL = KC >> 5;

    float* p = (isL1 ? p1 : p0) + (size_t)khalf * 393216;
    const int m = lane & 15, kg = lane >> 4;
    const int o0 = tile * 16;

    const float* wrow_a; const float* wrow_b = nullptr;
    const ushort *fhi, *flo;
    if (tile < 96) {
        wrow_a = (isL1 ? w_ih1 : w_ih0) + (size_t)(o0 + m) * IN;
        wrow_b = (isL1 ? w_hh1 : w_hh0) + (size_t)(o0 + m) * 512;
        fhi = fe + (isL1 ? FZ1H : FZ0H);  flo = fe + (isL1 ? FZ1L : FZ0L);
    } else if (tile < 128) {
        wrow_a = (isL1 ? kb1 : kb0) + (size_t)((tile - 96) * 16 + m) * W;
        fhi = fe + (isL1 ? FS1H : FS0H);  flo = fe + (isL1 ? FS1L : FS0L);
    } else {
        const int rr = (tile - 128) >> 5, op = ((tile - 128) & 31) * 16 + m;
        wrow_a = (isL1 ? swt1 : swt0) + ((size_t)rr * 512 + op) * W;
        fhi = fe + (isL1 ? FB1H : FB0H) + (size_t)rr * 64 * W;
        flo = fe + (isL1 ? FB1L : FB0L) + (size_t)rr * 64 * W;
    }

    f32x4 acc[4] = {{0,0,0,0},{0,0,0,0},{0,0,0,0},{0,0,0,0}};
    const int kbase = khalf * KC;

    for (int sl = 0; sl < NSL; ++sl) {
        const int k0 = kbase + sl * 32;
        const int kk = k0 + kg * 8;
        const float* wp = (tile < 96 && k0 >= IN) ? (wrow_b + (kk - IN)) : (wrow_a + kk);
        float4 wa = *(const float4*)wp;
        float4 wb4 = *(const float4*)(wp + 4);
        const float wvv[8] = {wa.x, wa.y, wa.z, wa.w, wb4.x, wb4.y, wb4.z, wb4.w};
        short8v whi, wlo;
#pragma unroll
        for (int j = 0; j < 8; ++j) {
            ushort h = bf16h(wvv[j]);
            whi[j] = (short)h;
            wlo[j] = (short)bf16h(wvv[j] - bf16f(h));
        }
#pragma unroll
        for (int bt = 0; bt < 4; ++bt) {
            const size_t fidx = (size_t)(bt * 16 + m) * W + kk;
            short8v bh = *(const short8v*)(fhi + fidx);
            short8v bl = *(const short8v*)(flo + fidx);
            acc[bt] = __builtin_amdgcn_mfma_f32_16x16x32_bf16(whi, bh, acc[bt], 0, 0, 0);
            acc[bt] = __builtin_amdgcn_mfma_f32_16x16x32_bf16(whi, bl, acc[bt], 0, 0, 0);
            acc[bt] = __builtin_amdgcn_mfma_f32_16x16x32_bf16(wlo, bh, acc[bt], 0, 0, 0);
        }
    }

#pragma unroll
    for (int bt = 0; bt < 4; ++bt) {
        float* dst = p + (size_t)(bt * 16 + m) * 6144 + o0 + kg * 4;
        *(float4*)dst = (float4){acc[bt][0], acc[bt][1], acc[bt][2], acc[bt][3]};
    }
}

// phase B: cell updates (sum nsplit K-slices) + feature generation; o-fast.
__global__ __launch_bounds__(256) void phaseB_kernel(
    ushort* __restrict__ fe, const float* __restrict__ p0, const float* __restrict__ p1,
    float* __restrict__ c0T, float* __restrict__ h1T, float* __restrict__ c1T,
    const float* __restrict__ b_ih0, const float* __restrict__ b_hh0,
    const float* __restrict__ b_ih1, const float* __restrict__ b_hh1,
    const float* __restrict__ x, int s, int nsplit)
{
    const int u = blockIdx.x * 256 + threadIdx.x;    // 288*256 = 73728
    if (u < 32768) {
        if (s >= TT) return;
        const int o = u & 511, b = u >> 9;
        auto P = [&](int rw) {
            float v = 0.f;
            for (int q = 0; q < nsplit; ++q)
                v += p0[(size_t)q * 393216 + (size_t)b * 6144 + rw];
            return v;
        };
        float si = P(o)        + b_ih0[o]        + b_hh0[o];
        float sf = P(512 + o)  + b_ih0[512 + o]  + b_hh0[512 + o];
        float sO = P(1024 + o) + b_ih0[1024 + o] + b_hh0[1024 + o];
        float sk = P(1536 + o);
#pragma unroll
        for (int rr = 0; rr < 8; ++rr) sk += P(2048 + rr * 512 + o);
        float ig = sigmoidf_(si), fg = sigmoidf_(sf), og = sigmoidf_(sO);
        float c = fg * c0T[(size_t)b * 512 + o] + ig * sk;
        c0T[(size_t)b * 512 + o] = c;
        float z = og * tanhf(c);
        write_featsT(z, fe, FZ1H, FZ1L, FS1H, FS1L, FB1H, FB1L,
                     65536, (size_t)b * 1024 + o);            // L1 input, t=s
        write_featsT(z, fe, FZ0H, FZ0L, FS0H, FS0L, FB0H, FB0L,
                     40960, (size_t)b * 640 + 128 + o);       // L0 hidden, t=s+1
    } else if (u < 65536) {
        if (s < 1) return;
        const int v = u - 32768, o = v & 511, b = v >> 9;
        auto P = [&](int rw) {
            float vv = 0.f;
            for (int q = 0; q < nsplit; ++q)
                vv += p1[(size_t)q * 393216 + (size_t)b * 6144 + rw];
            return vv;
        };
        float si = P(o)        + b_ih1[o]        + b_hh1[o];
        float sf = P(512 + o)  + b_ih1[512 + o]  + b_hh1[512 + o];
        float sO = P(1024 + o) + b_ih1[1024 + o] + b_hh1[1024 + o];
        float sk = P(1536 + o);
#pragma unroll
        for (int rr = 0; rr < 8; ++rr) sk += P(2048 + rr * 512 + o);
        float ig = sigmoidf_(si), fg = sigmoidf_(sf), og = sigmoidf_(sO);
        float c = fg * c1T[(size_t)b * 512 + o] + ig * sk;
        c1T[(size_t)b * 512 + o] = c;
        float z = og * tanhf(c);
        h1T[(size_t)b * 512 + o] = z;
        write_featsT(z, fe, FZ1H, FZ1L, FS1H, FS1L, FB1H, FB1L,
                     65536, (size_t)b * 1024 + 512 + o);      // L1 hidden, t=s
    } else {
        if (s + 1 >= TT) return;
        const int v = u - 65536, k = v & 127, b = v >> 7;
        float z = x[((size_t)b * TT + (s + 1)) * 128 + k];
        write_featsT(z, fe, FZ0H, FZ0L, FS0H, FS0L, FB0H, FB0L,
                     40960, (size_t)b * 640 + k);             // L0 x, t=s+1
    }
}

// out[b][jo] = h1T[b] . fc_w[jo] + fc_b[jo]  (fp32 out)
__global__ __launch_bounds__(256) void final_fc(
    const float* __restrict__ h1T, const float* __restrict__ fc_w,
    const float* __restrict__ fc_b, float* __restrict__ out)
{
    const int gid = blockIdx.x * 256 + threadIdx.x;   // 8192
    const int b = gid & 63, jo = gid >> 6;
    float a = fc_b[jo];
    const float* hr = h1T + (size_t)b * 512;
    const float* wr = fc_w + (size_t)jo * 512;
    for (int o = 0; o < 512; o += 4) {
        float4 h4 = *(const float4*)(hr + o);
        float4 w4 = *(const float4*)(wr + o);
        a = fmaf(h4.x, w4.x, a); a = fmaf(h4.y, w4.y, a);
        a = fmaf(h4.z, w4.z, a); a = fmaf(h4.w, w4.w, a);
    }
    out[(size_t)b * 128 + jo] = a;
}

} // namespace

extern "C" void kernel_launch(void* const* d_in, const int* in_sizes, int n_in,
                              void* d_out, int out_size, void* d_ws, size_t ws_size,
                              hipStream_t stream) {
    (void)out_size;
    float* out = (float*)d_out;

    static const int EXP_SIZES[15] = {
        64 * 256 * 128, 1536 * 128, 1536 * 512, 1536, 1536,
        512 * 640, 512 * 640 * 8,
        1536 * 512, 1536 * 512, 1536, 1536,
        512 * 1024, 512 * 1024 * 8,
        128 * 512, 128
    };
    if (n_in != 15) { sentinel_kernel<<<32, 256, 0, stream>>>(out, 111.0f); return; }
    for (int i = 0; i < 15; ++i)
        if (in_sizes[i] != EXP_SIZES[i]) {
            sentinel_kernel<<<32, 256, 0, stream>>>(out, 200.0f * (i + 1)); return;
        }
    if (ws_size < WS_SMALL) { sentinel_kernel<<<32, 256, 0, stream>>>(out, 7777.0f); return; }

    const float* x     = (const float*)d_in[0];
    const float* w_ih0 = (const float*)d_in[1];
    const float* w_hh0 = (const float*)d_in[2];
    const float* b_ih0 = (const float*)d_in[3];
    const float* b_hh0 = (const float*)d_in[4];
    const float* kb0   = (const float*)d_in[5];
    const float* ksp0  = (const float*)d_in[6];
    const float* w_ih1 = (const float*)d_in[7];
    const float* w_hh1 = (const float*)d_in[8];
    const float* b_ih1 = (const float*)d_in[9];
    const float* b_hh1 = (const float*)d_in[10];
    const float* kb1   = (const float*)d_in[11];
    const float* ksp1  = (const float*)d_in[12];
    const float* fc_w  = (const float*)d_in[13];
    const float* fc_b  = (const float*)d_in[14];

    float* ws = (float*)d_ws;

    if (ws_size >= WS_BIG) {
        // ---- BIG path: pre-split weights, K-quarter phaseA ----
        float* st = ws + B_ST;
        float* p0 = ws + B_P0;
        float* p1 = ws + B_P1;
        ushort* fe  = (ushort*)(ws + B_FEAT);
        ushort* wsp = (ushort*)(ws + B_WSP);

        prologue_kernel<<<672, 256, 0, stream>>>(x, st, fe);
        split_plain<<<768, 256, 0, stream>>>(w_ih0, wsp + WIH0H, wsp + WIH0L, 196608);
        split_plain<<<3072, 256, 0, stream>>>(w_hh0, wsp + WHH0H, wsp + WHH0L, 786432);
        split_plain<<<1280, 256, 0, stream>>>(kb0, wsp + KB0H, wsp + KB0L, 327680);
        split_plain<<<3072, 256, 0, stream>>>(w_ih1, wsp + WIH1H, wsp + WIH1L, 786432);
        split_plain<<<3072, 256, 0, stream>>>(w_hh1, wsp + WHH1H, wsp + WHH1L, 786432);
        split_plain<<<2048, 256, 0, stream>>>(kb1, wsp + KB1H, wsp + KB1L, 524288);
        split_swT<640><<<1280, 256, 0, stream>>>(ksp0, wsp + SWT0H, wsp + SWT0L);
        split_swT<1024><<<2048, 256, 0, stream>>>(ksp1, wsp + SWT1H, wsp + SWT1L);

        for (int s = 0; s <= TT; ++s) {
            phaseA_ps<<<768, 256, 0, stream>>>(fe, wsp, p0, p1, s);
            phaseB_kernel<<<288, 256, 0, stream>>>(fe, p0, p1, st, st + 32768,
                st + 65536, b_ih0, b_hh0, b_ih1, b_hh1, x, s, 4);
        }
        final_fc<<<32, 256, 0, stream>>>(st + 32768, fc_w, fc_b, out);
    } else {
        // ---- SMALL path: round-12 structure ----
        float* st   = ws + S_ST;
        float* p0   = ws + S_P0;
        float* p1   = ws + S_P1;
        float* swt0 = ws + S_SWT0;
        float* swt1 = ws + S_SWT1;
        ushort* fe  = (ushort*)(ws + S_FEAT);

        prologue_kernel<<<672, 256, 0, stream>>>(x, st, fe);
        transpose_sw<640><<<1280, 256, 0, stream>>>(ksp0, swt0);
        transpose_sw<1024><<<2048, 256, 0, stream>>>(ksp1, swt1);

        for (int s = 0; s <= TT; ++s) {
            phaseA_fb<<<768, 128, 0, stream>>>(fe, swt0, swt1, p0, p1,
                w_ih0, w_hh0, kb0, w_ih1, w_hh1, kb1, s);
            phaseB_kernel<<<288, 256, 0, stream>>>(fe, p0, p1, st, st + 32768,
                st + 65536, b_ih0, b_hh0, b_ih1, b_hh1, x, s, 2);
        }
        final_fc<<<32, 256, 0, stream>>>(st + 32768, fc_w, fc_b, out);
    }
}